// Round 1
// baseline (5534.668 us; speedup 1.0000x reference)
//
#include <hip/hip_runtime.h>
#include <hip/hip_bf16.h>

// Problem constants (B,N,D) = (4,4096,256), fp32.
#define BATCH 4
#define SEQ   4096
#define DIM   256
#define PROJ_ROWS 4

// ---------------------------------------------------------------------------
// Projection kernel: computes q,k,v rows for PROJ_ROWS consecutive sequence
// positions of ONE batch. Thread t owns output feature t (t in [0,256)).
// q[n][e] = sum_d x[n][d] * Wq[e][d] + bq[e]   (nn.Linear: x @ W^T + b)
// ---------------------------------------------------------------------------
__global__ __launch_bounds__(256) void proj_kernel(
    const float* __restrict__ x,                    // (SEQ, DIM) one batch
    const float* __restrict__ Wq, const float* __restrict__ bq,
    const float* __restrict__ Wk, const float* __restrict__ bk,
    const float* __restrict__ Wv, const float* __restrict__ bv,
    float* __restrict__ q, float* __restrict__ k, float* __restrict__ v)
{
    __shared__ float xs[PROJ_ROWS][DIM];
    const int n0 = blockIdx.x * PROJ_ROWS;
    const int t  = threadIdx.x;

    #pragma unroll
    for (int r = 0; r < PROJ_ROWS; ++r)
        xs[r][t] = x[(size_t)(n0 + r) * DIM + t];
    __syncthreads();

    float aq[PROJ_ROWS] = {0.f, 0.f, 0.f, 0.f};
    float ak[PROJ_ROWS] = {0.f, 0.f, 0.f, 0.f};
    float av[PROJ_ROWS] = {0.f, 0.f, 0.f, 0.f};

    const float4* wq4 = (const float4*)(Wq + (size_t)t * DIM);
    const float4* wk4 = (const float4*)(Wk + (size_t)t * DIM);
    const float4* wv4 = (const float4*)(Wv + (size_t)t * DIM);

    for (int d4 = 0; d4 < DIM / 4; ++d4) {
        const float4 wq = wq4[d4];
        const float4 wk = wk4[d4];
        const float4 wv = wv4[d4];
        #pragma unroll
        for (int r = 0; r < PROJ_ROWS; ++r) {
            const float x0 = xs[r][4 * d4 + 0];
            const float x1 = xs[r][4 * d4 + 1];
            const float x2 = xs[r][4 * d4 + 2];
            const float x3 = xs[r][4 * d4 + 3];
            aq[r] = fmaf(wq.x, x0, fmaf(wq.y, x1, fmaf(wq.z, x2, fmaf(wq.w, x3, aq[r]))));
            ak[r] = fmaf(wk.x, x0, fmaf(wk.y, x1, fmaf(wk.z, x2, fmaf(wk.w, x3, ak[r]))));
            av[r] = fmaf(wv.x, x0, fmaf(wv.y, x1, fmaf(wv.z, x2, fmaf(wv.w, x3, av[r]))));
        }
    }

    #pragma unroll
    for (int r = 0; r < PROJ_ROWS; ++r) {
        const size_t o = (size_t)(n0 + r) * DIM + t;
        q[o] = aq[r] + bq[t];
        k[o] = ak[r] + bk[t];
        v[o] = av[r] + bv[t];
    }
}

// ---------------------------------------------------------------------------
// Block-wide reductions (256 threads = 4 waves of 64)
// ---------------------------------------------------------------------------
__device__ inline float wave_max64(float v) {
    #pragma unroll
    for (int o = 32; o > 0; o >>= 1) v = fmaxf(v, __shfl_xor(v, o));
    return v;
}
__device__ inline float wave_sum64(float v) {
    #pragma unroll
    for (int o = 32; o > 0; o >>= 1) v += __shfl_xor(v, o);
    return v;
}
__device__ inline float block_max(float v, float* red) {
    v = wave_max64(v);
    const int w = threadIdx.x >> 6;
    if ((threadIdx.x & 63) == 0) red[w] = v;
    __syncthreads();
    v = fmaxf(fmaxf(red[0], red[1]), fmaxf(red[2], red[3]));
    __syncthreads();
    return v;
}
__device__ inline float block_sum(float v, float* red) {
    v = wave_sum64(v);
    const int w = threadIdx.x >> 6;
    if ((threadIdx.x & 63) == 0) red[w] = v;
    __syncthreads();
    v = red[0] + red[1] + red[2] + red[3];
    __syncthreads();
    return v;
}

// ---------------------------------------------------------------------------
// Flash-style causal attention, fp32, NO 1/sqrt(d) scaling.
// One block (256 threads) per query row n. Tiles of 256 keys:
//   phase 1: thread j computes score s_j = q_n . k_j  (online max/sum update)
//   phase 2: thread d accumulates out[n][d] += w_j * v[j][d] (coalesced)
// ---------------------------------------------------------------------------
__global__ __launch_bounds__(256) void attn_kernel(
    const float* __restrict__ q, const float* __restrict__ k,
    const float* __restrict__ v, float* __restrict__ out)   // (SEQ, DIM)
{
    __shared__ float qs[DIM];
    __shared__ float sc[256];
    __shared__ float red[4];

    const int n = blockIdx.x;   // query row
    const int t = threadIdx.x;
    const int nk = n + 1;       // causal: keys 0..n inclusive

    qs[t] = q[(size_t)n * DIM + t];
    __syncthreads();

    float m = -__builtin_inff();
    float l = 0.f;
    float acc = 0.f;            // out[n][t]

    for (int base = 0; base < nk; base += 256) {
        const int j = base + t;
        float s = -__builtin_inff();
        if (j < nk) {
            const float4* kr4 = (const float4*)(k + (size_t)j * DIM);
            float sum = 0.f;
            #pragma unroll 8
            for (int d4 = 0; d4 < DIM / 4; ++d4) {
                const float4 kk = kr4[d4];
                sum = fmaf(kk.x, qs[4 * d4 + 0],
                      fmaf(kk.y, qs[4 * d4 + 1],
                      fmaf(kk.z, qs[4 * d4 + 2],
                      fmaf(kk.w, qs[4 * d4 + 3], sum))));
            }
            s = sum;
        }
        const float tmax  = block_max(s, red);
        const float m_new = fmaxf(m, tmax);
        const float scale = expf(m - m_new);           // first iter: exp(-inf)=0
        const float w = (j < nk) ? expf(s - m_new) : 0.f;
        const float tsum = block_sum(w, red);
        l = l * scale + tsum;
        m = m_new;

        sc[t] = w;
        __syncthreads();

        acc *= scale;
        const int jend = min(256, nk - base);
        for (int jj = 0; jj < jend; ++jj)
            acc = fmaf(sc[jj], v[(size_t)(base + jj) * DIM + t], acc);
        __syncthreads();
    }

    out[(size_t)n * DIM + t] = acc / l;
}

// ---------------------------------------------------------------------------
// Launch: per-batch loop (needs only 12 MB of workspace: q,k,v fp32 for one
// batch). Same-stream ordering serializes proj(b) -> attn(b).
// ---------------------------------------------------------------------------
extern "C" void kernel_launch(void* const* d_in, const int* in_sizes, int n_in,
                              void* d_out, int out_size, void* d_ws, size_t ws_size,
                              hipStream_t stream) {
    const float* x  = (const float*)d_in[0];
    const float* Wq = (const float*)d_in[1];
    const float* bq = (const float*)d_in[2];
    const float* Wk = (const float*)d_in[3];
    const float* bk = (const float*)d_in[4];
    const float* Wv = (const float*)d_in[5];
    const float* bv = (const float*)d_in[6];
    float* out = (float*)d_out;

    float* qw = (float*)d_ws;                 // SEQ*DIM fp32
    float* kw = qw + (size_t)SEQ * DIM;       // SEQ*DIM fp32
    float* vw = kw + (size_t)SEQ * DIM;       // SEQ*DIM fp32

    for (int b = 0; b < BATCH; ++b) {
        const float* xb = x + (size_t)b * SEQ * DIM;
        proj_kernel<<<SEQ / PROJ_ROWS, 256, 0, stream>>>(
            xb, Wq, bq, Wk, bk, Wv, bv, qw, kw, vw);
        attn_kernel<<<SEQ, 256, 0, stream>>>(
            qw, kw, vw, out + (size_t)b * SEQ * DIM);
    }
}

// Round 3
// 840.424 us; speedup vs baseline: 6.5856x; 6.5856x over previous
//
#include <hip/hip_runtime.h>
#include <hip/hip_bf16.h>

// (B,N,D) = (4,4096,256) fp32 in/out. MFMA fp16-split pipeline:
//  proj (3-term fp16 split MFMA) -> qh,ql (Q pre-scaled by log2e), kh, v
//  transpose v -> vT[d][n]
//  attn: flash, swapped QK^T (S^T = K*Q^T), exp2-domain softmax, defer-max,
//        K in LDS (swizzled, double-buffered), V frags streamed from global.

#define SEQ   4096
#define DIM   256
#define LOG2E 1.4426950408889634f

typedef _Float16 f16;
typedef __attribute__((ext_vector_type(8)))  f16    f16x8;
typedef __attribute__((ext_vector_type(2)))  __fp16 pk16x2;   // cvt_pkrtz native type
typedef __attribute__((ext_vector_type(16))) float  f32x16;

// ---------------------------------------------------------------------------
// Projection: Y[m][e] = sum_d X[m][d]*W[e][d] + b[e], scaled, fp16 hi(+lo) out.
// Block: 64 rows x 256 cols, 4 waves. Wave: (w&1) row-half, (w>>1) col-half.
// mfma_f32_32x32x16_f16: A lane l: A[l%32][8*(l/32)+i]; B: B[8*(l/32)+i][l%32];
// D lane l reg r: D[(r&3)+8*(r>>2)+4*(l>>5)][l&31].
// ---------------------------------------------------------------------------
__global__ __launch_bounds__(256) void proj_mfma(
    const float* __restrict__ X, const float* __restrict__ W,
    const float* __restrict__ bias, f16* __restrict__ outH,
    f16* __restrict__ outL, float scale)
{
    const int w = threadIdx.x >> 6, lane = threadIdx.x & 63;
    const int col = lane & 31, hi = lane >> 5;
    const int m0 = blockIdx.x * 64 + (w & 1) * 32;
    const int e0 = (w >> 1) * 128;

    f32x16 acc[4] = {};
    for (int s = 0; s < 16; ++s) {
        const float* xp = X + (size_t)(m0 + col) * DIM + s * 16 + 8 * hi;
        float xv[8];
        *(float4*)&xv[0] = *(const float4*)xp;
        *(float4*)&xv[4] = *(const float4*)(xp + 4);
        f16x8 xh, xl;
        #pragma unroll
        for (int i = 0; i < 8; ++i) {
            xh[i] = (f16)xv[i];
            xl[i] = (f16)(xv[i] - (float)xh[i]);
        }
        #pragma unroll
        for (int c = 0; c < 4; ++c) {
            const float* wp = W + (size_t)(e0 + c * 32 + col) * DIM + s * 16 + 8 * hi;
            float wv[8];
            *(float4*)&wv[0] = *(const float4*)wp;
            *(float4*)&wv[4] = *(const float4*)(wp + 4);
            f16x8 wh, wl;
            #pragma unroll
            for (int i = 0; i < 8; ++i) {
                wh[i] = (f16)wv[i];
                wl[i] = (f16)(wv[i] - (float)wh[i]);
            }
            acc[c] = __builtin_amdgcn_mfma_f32_32x32x16_f16(xh, wh, acc[c], 0, 0, 0);
            acc[c] = __builtin_amdgcn_mfma_f32_32x32x16_f16(xl, wh, acc[c], 0, 0, 0);
            acc[c] = __builtin_amdgcn_mfma_f32_32x32x16_f16(xh, wl, acc[c], 0, 0, 0);
        }
    }
    #pragma unroll
    for (int c = 0; c < 4; ++c) {
        const int e = e0 + c * 32 + col;
        const float b = bias[e];
        #pragma unroll
        for (int r = 0; r < 16; ++r) {
            const int m = m0 + (r & 3) + 8 * (r >> 2) + 4 * hi;
            const float y = (acc[c][r] + b) * scale;
            const f16 yh = (f16)y;
            const size_t o = (size_t)m * DIM + e;
            outH[o] = yh;
            if (outL) outL[o] = (f16)(y - (float)yh);
        }
    }
}

// ---------------------------------------------------------------------------
// v (fp16 [N][256] per batch) -> vT (fp16 [256][N] per batch)
// ---------------------------------------------------------------------------
__global__ void transpose_v(const f16* __restrict__ v, f16* __restrict__ vT)
{
    __shared__ f16 tile[32][33];
    const size_t pp = (size_t)SEQ * DIM;
    const f16* vb = v + blockIdx.z * pp;
    f16* vTb = vT + blockIdx.z * pp;
    const int n0 = blockIdx.x * 32, e0 = blockIdx.y * 32;
    #pragma unroll
    for (int r = 0; r < 4; ++r)
        tile[threadIdx.y + 8 * r][threadIdx.x] =
            vb[(size_t)(n0 + threadIdx.y + 8 * r) * DIM + e0 + threadIdx.x];
    __syncthreads();
    #pragma unroll
    for (int r = 0; r < 4; ++r)
        vTb[(size_t)(e0 + threadIdx.y + 8 * r) * SEQ + n0 + threadIdx.x] =
            tile[threadIdx.x][threadIdx.y + 8 * r];
}

// ---------------------------------------------------------------------------
// Flash attention. Grid: x = 64 q-tiles (64 rows), y = nbatch. 2 waves/block,
// each wave owns 32 q-rows. KV tile = 32 keys. Scores in exp2 domain.
// ---------------------------------------------------------------------------
__global__ __launch_bounds__(128, 1) void attn_mfma(
    const f16* __restrict__ qh, const f16* __restrict__ ql,
    const f16* __restrict__ kh, const f16* __restrict__ vT,
    float* __restrict__ out, int nbatch)
{
    int qt, b;
    if (nbatch == 4) {          // XCD-aware swizzle: 2 XCDs per batch
        const int lin = blockIdx.x + 64 * blockIdx.y;
        const int x8 = lin & 7;
        b = x8 >> 1;
        qt = ((x8 & 1) << 5) + (lin >> 3);
    } else {
        qt = blockIdx.x; b = blockIdx.y;
    }
    const size_t pp = (size_t)SEQ * DIM;
    const f16* qhb = qh + b * pp;
    const f16* qlb = ql + b * pp;
    const f16* khb = kh + b * pp;
    const f16* vTb = vT + b * pp;   // [256][4096]
    float* outb = out + b * pp;

    const int wid = threadIdx.x >> 6, lane = threadIdx.x & 63;
    const int col = lane & 31, hi = lane >> 5;
    const int q0w = qt * 64 + wid * 32;
    const int nt = 2 * qt + 2;

    // Q fragments resident (hi+lo)
    f16x8 qhf[16], qlf[16];
    #pragma unroll
    for (int s = 0; s < 16; ++s) {
        const size_t off = (size_t)(q0w + col) * DIM + s * 16 + 8 * hi;
        qhf[s] = *(const f16x8*)(qhb + off);
        qlf[s] = *(const f16x8*)(qlb + off);
    }

    __shared__ uint4 ldsK[2][1024];   // 2 x 16KB, swizzled: slot ^= row

    // prologue: stage tile 0
    {
        #pragma unroll
        for (int i = 0; i < 8; ++i) {
            const int c = wid * 512 + i * 64 + lane;
            const int row = c >> 5, slot = c & 31;
            const uint4 d = *(const uint4*)((const char*)khb + (size_t)row * 512 + slot * 16);
            ldsK[0][row * 32 + (slot ^ row)] = d;
        }
    }
    __syncthreads();

    float m_run = -1e30f, l_run = 0.f;
    f32x16 oacc[8] = {};
    int buf = 0;

    for (int t = 0; t < nt; ++t) {
        const int j0 = t * 32;
        const bool do_stage = (t + 1 < nt);
        uint4 kreg[8];
        if (do_stage) {
            const int j0n = j0 + 32;
            #pragma unroll
            for (int i = 0; i < 8; ++i) {
                const int c = wid * 512 + i * 64 + lane;
                const int row = c >> 5, slot = c & 31;
                kreg[i] = *(const uint4*)((const char*)khb + (size_t)(j0n + row) * 512 + slot * 16);
            }
        }
        if (j0 <= q0w + 31) {       // wave-uniform
            // V frags, first half (c=0..3), issued early to hide L2 latency
            f16x8 vbA[4][2];
            #pragma unroll
            for (int c = 0; c < 4; ++c) {
                const f16* vp = vTb + (size_t)(32 * c + col) * SEQ + j0 + 8 * hi;
                vbA[c][0] = *(const f16x8*)vp;
                vbA[c][1] = *(const f16x8*)(vp + 16);
            }
            // QK^T (swapped): S^T[key][q]
            f32x16 s = {};
            const char* kb = (const char*)&ldsK[buf][0];
            #pragma unroll
            for (int sl = 0; sl < 16; ++sl) {
                const int slotr = (2 * sl + hi) ^ col;
                const f16x8 kf = *(const f16x8*)(kb + (size_t)col * 512 + slotr * 16);
                s = __builtin_amdgcn_mfma_f32_32x32x16_f16(kf, qhf[sl], s, 0, 0, 0);
                s = __builtin_amdgcn_mfma_f32_32x32x16_f16(kf, qlf[sl], s, 0, 0, 0);
            }
            // V frags, second half
            f16x8 vbB[4][2];
            #pragma unroll
            for (int c = 0; c < 4; ++c) {
                const f16* vp = vTb + (size_t)(32 * (c + 4) + col) * SEQ + j0 + 8 * hi;
                vbB[c][0] = *(const f16x8*)vp;
                vbB[c][1] = *(const f16x8*)(vp + 16);
            }
            // mask + online softmax (per lane: 16 keys for q = q0w+col)
            float p[16];
            float pmax = -1e30f;
            #pragma unroll
            for (int r = 0; r < 16; ++r) {
                const int kr = (r & 3) + 8 * (r >> 2) + 4 * hi;
                const float sv = ((j0 + kr) <= (q0w + col)) ? s[r] : -1e30f;
                p[r] = sv;
                pmax = fmaxf(pmax, sv);
            }
            pmax = fmaxf(pmax, __shfl_xor(pmax, 32));
            if (__any(pmax > m_run + 11.5415603f)) {   // defer-max (8 nats)
                const float mnew = fmaxf(m_run, pmax);
                const float sc = exp2f(m_run - mnew);
                l_run *= sc;
                m_run = mnew;
                #pragma unroll
                for (int r = 0; r < 16; ++r) {
                    const int qr = ((r & 3) + 8 * (r >> 2) + 4 * hi) | (lane & 32);
                    const float scr = __shfl(sc, qr);
                    #pragma unroll
                    for (int c = 0; c < 8; ++c) oacc[c][r] *= scr;
                }
            }
            float tsum = 0.f;
            #pragma unroll
            for (int r = 0; r < 16; ++r) {
                p[r] = exp2f(p[r] - m_run);
                tsum += p[r];
            }
            tsum += __shfl_xor(tsum, 32);
            l_run += tsum;
            // P -> A fragments (cvt_pkrtz + half-swap)
            uint32_t Wd[8], Od[8];
            #pragma unroll
            for (int j = 0; j < 8; ++j) {
                const pk16x2 pk = __builtin_amdgcn_cvt_pkrtz(p[2 * j], p[2 * j + 1]);
                Wd[j] = __builtin_bit_cast(uint32_t, pk);
            }
            #pragma unroll
            for (int j = 0; j < 8; ++j)
                Od[j] = (uint32_t)__shfl_xor((int)Wd[j], 32);
            union H8 { uint32_t u[4]; f16x8 v; } A0, A1;
            if (hi == 0) {
                A0.u[0] = Wd[0]; A0.u[1] = Wd[1]; A0.u[2] = Od[0]; A0.u[3] = Od[1];
                A1.u[0] = Wd[4]; A1.u[1] = Wd[5]; A1.u[2] = Od[4]; A1.u[3] = Od[5];
            } else {
                A0.u[0] = Od[2]; A0.u[1] = Od[3]; A0.u[2] = Wd[2]; A0.u[3] = Wd[3];
                A1.u[0] = Od[6]; A1.u[1] = Od[7]; A1.u[2] = Wd[6]; A1.u[3] = Wd[7];
            }
            // PV
            #pragma unroll
            for (int c = 0; c < 4; ++c) {
                oacc[c] = __builtin_amdgcn_mfma_f32_32x32x16_f16(A0.v, vbA[c][0], oacc[c], 0, 0, 0);
                oacc[c] = __builtin_amdgcn_mfma_f32_32x32x16_f16(A1.v, vbA[c][1], oacc[c], 0, 0, 0);
            }
            #pragma unroll
            for (int c = 0; c < 4; ++c) {
                oacc[c + 4] = __builtin_amdgcn_mfma_f32_32x32x16_f16(A0.v, vbB[c][0], oacc[c + 4], 0, 0, 0);
                oacc[c + 4] = __builtin_amdgcn_mfma_f32_32x32x16_f16(A1.v, vbB[c][1], oacc[c + 4], 0, 0, 0);
            }
        }
        __syncthreads();
        if (do_stage) {
            #pragma unroll
            for (int i = 0; i < 8; ++i) {
                const int c = wid * 512 + i * 64 + lane;
                const int row = c >> 5, slot = c & 31;
                ldsK[buf ^ 1][row * 32 + (slot ^ row)] = kreg[i];
            }
        }
        __syncthreads();
        buf ^= 1;
    }

    // epilogue: divide by l, store fp32
    const float linv = 1.f / l_run;
    #pragma unroll
    for (int r = 0; r < 16; ++r) {
        const int qr0 = (r & 3) + 8 * (r >> 2) + 4 * hi;
        const float lr = __shfl(linv, qr0 | (lane & 32));
        const int n = q0w + qr0;
        #pragma unroll
        for (int c = 0; c < 8; ++c)
            outb[(size_t)n * DIM + 32 * c + col] = oacc[c][r] * lr;
    }
}

// ---------------------------------------------------------------------------
extern "C" void kernel_launch(void* const* d_in, const int* in_sizes, int n_in,
                              void* d_out, int out_size, void* d_ws, size_t ws_size,
                              hipStream_t stream) {
    const float* x  = (const float*)d_in[0];
    const float* Wq = (const float*)d_in[1];
    const float* bq = (const float*)d_in[2];
    const float* Wk = (const float*)d_in[3];
    const float* bk = (const float*)d_in[4];
    const float* Wv = (const float*)d_in[5];
    const float* bv = (const float*)d_in[6];
    float* out = (float*)d_out;

    const size_t PP = (size_t)SEQ * DIM;            // per-batch plane elems
    const size_t FULL = 4 * PP;                     // all-batch plane elems

    if (ws_size >= FULL * 2 * 5) {
        // full-batch path: 5 fp16 planes of 8MB
        f16* qh = (f16*)d_ws;
        f16* ql = qh + FULL;
        f16* kh = ql + FULL;
        f16* vv = kh + FULL;
        f16* vT = vv + FULL;
        proj_mfma<<<dim3(256), 256, 0, stream>>>(x, Wq, bq, qh, ql, LOG2E);
        proj_mfma<<<dim3(256), 256, 0, stream>>>(x, Wk, bk, kh, nullptr, 1.f);
        proj_mfma<<<dim3(256), 256, 0, stream>>>(x, Wv, bv, vv, nullptr, 1.f);
        transpose_v<<<dim3(128, 8, 4), dim3(32, 8), 0, stream>>>(vv, vT);
        attn_mfma<<<dim3(64, 4), 128, 0, stream>>>(qh, ql, kh, vT, out, 4);
    } else {
        // per-batch fallback (10.5 MB of ws)
        f16* qh = (f16*)d_ws;
        f16* ql = qh + PP;
        f16* kh = ql + PP;
        f16* vv = kh + PP;
        f16* vT = vv + PP;
        for (int b = 0; b < 4; ++b) {
            const float* xb = x + b * PP;
            proj_mfma<<<dim3(64), 256, 0, stream>>>(xb, Wq, bq, qh, ql, LOG2E);
            proj_mfma<<<dim3(64), 256, 0, stream>>>(xb, Wk, bk, kh, nullptr, 1.f);
            proj_mfma<<<dim3(64), 256, 0, stream>>>(xb, Wv, bv, vv, nullptr, 1.f);
            transpose_v<<<dim3(128, 8, 1), dim3(32, 8), 0, stream>>>(vv, vT);
            attn_mfma<<<dim3(64, 1), 128, 0, stream>>>(qh, ql, kh, vT, out + b * PP, 1);
        }
    }
}

// Round 4
// 279.502 us; speedup vs baseline: 19.8019x; 3.0069x over previous
//
#include <hip/hip_runtime.h>
#include <hip/hip_bf16.h>

// (B,N,D) = (4,4096,256) fp32 in/out. MFMA fp16-split pipeline:
//  proj (3-term fp16 split MFMA) -> qh,ql (Q pre-scaled by log2e), kh, v
//  transpose v -> vT[d][n]
//  attn: flash, 32-row q-tiles, 4 waves/block (key-split QK^T, col-split PV),
//        P exchanged via double-buffered swizzled LDS, K/V streamed from L2.

#define SEQ   4096
#define DIM   256
#define LOG2E 1.4426950408889634f

typedef _Float16 f16;
typedef __attribute__((ext_vector_type(8)))  f16    f16x8;
typedef __attribute__((ext_vector_type(2)))  __fp16 pk16x2;   // cvt_pkrtz native type
typedef __attribute__((ext_vector_type(16))) float  f32x16;

// ---------------------------------------------------------------------------
// Projection: Y[m][e] = sum_d X[m][d]*W[e][d] + b[e], scaled, fp16 hi(+lo) out.
// Block: 64 rows x 256 cols, 4 waves. (unchanged from round 3 — verified)
// ---------------------------------------------------------------------------
__global__ __launch_bounds__(256) void proj_mfma(
    const float* __restrict__ X, const float* __restrict__ W,
    const float* __restrict__ bias, f16* __restrict__ outH,
    f16* __restrict__ outL, float scale)
{
    const int w = threadIdx.x >> 6, lane = threadIdx.x & 63;
    const int col = lane & 31, hi = lane >> 5;
    const int m0 = blockIdx.x * 64 + (w & 1) * 32;
    const int e0 = (w >> 1) * 128;

    f32x16 acc[4] = {};
    for (int s = 0; s < 16; ++s) {
        const float* xp = X + (size_t)(m0 + col) * DIM + s * 16 + 8 * hi;
        float xv[8];
        *(float4*)&xv[0] = *(const float4*)xp;
        *(float4*)&xv[4] = *(const float4*)(xp + 4);
        f16x8 xh, xl;
        #pragma unroll
        for (int i = 0; i < 8; ++i) {
            xh[i] = (f16)xv[i];
            xl[i] = (f16)(xv[i] - (float)xh[i]);
        }
        #pragma unroll
        for (int c = 0; c < 4; ++c) {
            const float* wp = W + (size_t)(e0 + c * 32 + col) * DIM + s * 16 + 8 * hi;
            float wv[8];
            *(float4*)&wv[0] = *(const float4*)wp;
            *(float4*)&wv[4] = *(const float4*)(wp + 4);
            f16x8 wh, wl;
            #pragma unroll
            for (int i = 0; i < 8; ++i) {
                wh[i] = (f16)wv[i];
                wl[i] = (f16)(wv[i] - (float)wh[i]);
            }
            acc[c] = __builtin_amdgcn_mfma_f32_32x32x16_f16(xh, wh, acc[c], 0, 0, 0);
            acc[c] = __builtin_amdgcn_mfma_f32_32x32x16_f16(xl, wh, acc[c], 0, 0, 0);
            acc[c] = __builtin_amdgcn_mfma_f32_32x32x16_f16(xh, wl, acc[c], 0, 0, 0);
        }
    }
    #pragma unroll
    for (int c = 0; c < 4; ++c) {
        const int e = e0 + c * 32 + col;
        const float b = bias[e];
        #pragma unroll
        for (int r = 0; r < 16; ++r) {
            const int m = m0 + (r & 3) + 8 * (r >> 2) + 4 * hi;
            const float y = (acc[c][r] + b) * scale;
            const f16 yh = (f16)y;
            const size_t o = (size_t)m * DIM + e;
            outH[o] = yh;
            if (outL) outL[o] = (f16)(y - (float)yh);
        }
    }
}

// ---------------------------------------------------------------------------
// v (fp16 [N][256] per batch) -> vT (fp16 [256][N] per batch)
// ---------------------------------------------------------------------------
__global__ void transpose_v(const f16* __restrict__ v, f16* __restrict__ vT)
{
    __shared__ f16 tile[32][33];
    const size_t pp = (size_t)SEQ * DIM;
    const f16* vb = v + blockIdx.z * pp;
    f16* vTb = vT + blockIdx.z * pp;
    const int n0 = blockIdx.x * 32, e0 = blockIdx.y * 32;
    #pragma unroll
    for (int r = 0; r < 4; ++r)
        tile[threadIdx.y + 8 * r][threadIdx.x] =
            vb[(size_t)(n0 + threadIdx.y + 8 * r) * DIM + e0 + threadIdx.x];
    __syncthreads();
    #pragma unroll
    for (int r = 0; r < 4; ++r)
        vTb[(size_t)(e0 + threadIdx.y + 8 * r) * SEQ + n0 + threadIdx.x] =
            tile[threadIdx.x][threadIdx.y + 8 * r];
}

// ---------------------------------------------------------------------------
// Flash attention, 32-row q-tile, 4 waves (key-split QK^T, col-split PV).
// Per 128-key iteration:
//   wave w: QK^T for keys [j0+32w, j0+32w+32)  (K frags direct from global)
//   LDS max-exchange -> block m_new; rescale oacc; p = exp2(s - m_new)
//   P (fp16) -> swizzled LDS [q][128keys], double-buffered
//   PV: wave w owns output cols [64w, 64w+64) over all 128 keys
// ---------------------------------------------------------------------------
__global__ __launch_bounds__(256, 2) void attn_flash(
    const f16* __restrict__ qh, const f16* __restrict__ ql,
    const f16* __restrict__ kh, const f16* __restrict__ vT,
    float* __restrict__ out, int nbatch)
{
    int qt, b;
    if (nbatch == 4) {
        const int lin = blockIdx.x;          // 512 blocks
        b = (lin & 7) >> 1;                  // 2 XCDs per batch
        qt = ((lin >> 3) << 1) | (lin & 1);  // even/odd interleave (balance)
    } else {
        qt = blockIdx.x; b = 0;
    }
    const size_t pp = (size_t)SEQ * DIM;
    const f16* qhb = qh + b * pp;
    const f16* qlb = ql + b * pp;
    const f16* khb = kh + b * pp;
    const f16* vTb = vT + b * pp;            // [256][4096]
    float* outb = out + b * pp;

    const int wid = threadIdx.x >> 6, lane = threadIdx.x & 63;
    const int col = lane & 31, hi = lane >> 5;
    const int q0 = qt * 32;
    const int qend = q0 + 32;
    const int niter = (qend + 127) >> 7;

    // Q fragments resident (hi+lo): rows q0..q0+31 (same for all 4 waves)
    f16x8 qhf[16], qlf[16];
    #pragma unroll
    for (int s = 0; s < 16; ++s) {
        const size_t off = (size_t)(q0 + col) * DIM + s * 16 + 8 * hi;
        qhf[s] = *(const f16x8*)(qhb + off);
        qlf[s] = *(const f16x8*)(qlb + off);
    }

    __shared__ uint4 Pbuf[2][32][16];        // [buf][q][128 keys fp16] = 2x8KB
    __shared__ float mbuf[2][4][32];
    __shared__ float lbuf[2][4][32];

    float m_run = -1e30f, l_run = 0.f;
    f32x16 oacc[2] = {};                     // cols 32*(2*wid+cc)+col

    for (int it = 0; it < niter; ++it) {
        const int j0 = it << 7;
        const int nk = min(128, qend - j0);
        const int pb = it & 1;
        const bool active = (32 * wid) < nk;

        float sv[16];
        float pmax = -1e30f;
        if (active) {
            const int jw = j0 + 32 * wid;
            const f16* kbase = khb + (size_t)(jw + col) * DIM + 8 * hi;
            f32x16 s1 = {}, s2 = {};
            #pragma unroll
            for (int sl = 0; sl < 16; ++sl) {
                const f16x8 kf = *(const f16x8*)(kbase + sl * 16);
                s1 = __builtin_amdgcn_mfma_f32_32x32x16_f16(kf, qhf[sl], s1, 0, 0, 0);
                s2 = __builtin_amdgcn_mfma_f32_32x32x16_f16(kf, qlf[sl], s2, 0, 0, 0);
            }
            #pragma unroll
            for (int r = 0; r < 16; ++r) {
                const int kg = jw + (r & 3) + 8 * (r >> 2) + 4 * hi;
                const float x = (kg <= q0 + col) ? (s1[r] + s2[r]) : -1e30f;
                sv[r] = x;
                pmax = fmaxf(pmax, x);
            }
            pmax = fmaxf(pmax, __shfl_xor(pmax, 32));
        }
        if (lane < 32) mbuf[pb][wid][col] = pmax;
        __syncthreads();                     // bar1: pmax visible

        const float mx = fmaxf(fmaxf(mbuf[pb][0][col], mbuf[pb][1][col]),
                               fmaxf(mbuf[pb][2][col], mbuf[pb][3][col]));
        const float m_new = fmaxf(m_run, mx);
        const float scale = exp2f(m_run - m_new);
        m_run = m_new;
        #pragma unroll
        for (int r = 0; r < 16; ++r) {       // rescale oacc per q-row
            const int qr = (r & 3) + 8 * (r >> 2) + 4 * hi;
            const float scr = __shfl(scale, qr | (lane & 32));
            oacc[0][r] *= scr;
            oacc[1][r] *= scr;
        }

        float tsum = 0.f;
        if (active) {
            float p[16];
            #pragma unroll
            for (int r = 0; r < 16; ++r) {
                p[r] = exp2f(sv[r] - m_new);
                tsum += p[r];
            }
            tsum += __shfl_xor(tsum, 32);
            // pack pairs (adjacent keys) and write swizzled P row
            char* prow = (char*)&Pbuf[pb][0][0] + col * 256;
            const int swz = (col & 15) << 4;
            #pragma unroll
            for (int j = 0; j < 8; ++j) {
                const pk16x2 pk = __builtin_amdgcn_cvt_pkrtz(p[2 * j], p[2 * j + 1]);
                const int kb2 = 64 * wid + 2 * (((2 * j) & 3) + 8 * (j >> 1) + 4 * hi);
                *(uint32_t*)(prow + (kb2 ^ swz)) = __builtin_bit_cast(uint32_t, pk);
            }
        }
        if (lane < 32) lbuf[pb][wid][col] = tsum;
        __syncthreads();                     // bar2: P + tile-sums visible

        l_run = l_run * scale +
                (lbuf[pb][0][col] + lbuf[pb][1][col] + lbuf[pb][2][col] + lbuf[pb][3][col]);

        // PV over all nk keys, own col-quarter
        const int nslice = (nk + 15) >> 4;
        const char* prow = (const char*)&Pbuf[pb][0][0] + col * 256;
        const int swz = (col & 15) << 4;
        const f16* vbase0 = vTb + (size_t)(32 * (2 * wid + 0) + col) * SEQ + j0 + 8 * hi;
        const f16* vbase1 = vTb + (size_t)(32 * (2 * wid + 1) + col) * SEQ + j0 + 8 * hi;
        for (int sl2 = 0; sl2 < nslice; ++sl2) {
            const f16x8 af = *(const f16x8*)(prow + ((32 * sl2 + 16 * hi) ^ swz));
            oacc[0] = __builtin_amdgcn_mfma_f32_32x32x16_f16(
                af, *(const f16x8*)(vbase0 + 16 * sl2), oacc[0], 0, 0, 0);
            oacc[1] = __builtin_amdgcn_mfma_f32_32x32x16_f16(
                af, *(const f16x8*)(vbase1 + 16 * sl2), oacc[1], 0, 0, 0);
        }
    }

    // epilogue: divide by l, store fp32
    const float linv = 1.f / l_run;
    #pragma unroll
    for (int r = 0; r < 16; ++r) {
        const int qr = (r & 3) + 8 * (r >> 2) + 4 * hi;
        const float lr = __shfl(linv, qr | (lane & 32));
        const int n = q0 + qr;
        outb[(size_t)n * DIM + 32 * (2 * wid + 0) + col] = oacc[0][r] * lr;
        outb[(size_t)n * DIM + 32 * (2 * wid + 1) + col] = oacc[1][r] * lr;
    }
}

// ---------------------------------------------------------------------------
extern "C" void kernel_launch(void* const* d_in, const int* in_sizes, int n_in,
                              void* d_out, int out_size, void* d_ws, size_t ws_size,
                              hipStream_t stream) {
    const float* x  = (const float*)d_in[0];
    const float* Wq = (const float*)d_in[1];
    const float* bq = (const float*)d_in[2];
    const float* Wk = (const float*)d_in[3];
    const float* bk = (const float*)d_in[4];
    const float* Wv = (const float*)d_in[5];
    const float* bv = (const float*)d_in[6];
    float* out = (float*)d_out;

    const size_t PP = (size_t)SEQ * DIM;            // per-batch plane elems
    const size_t FULL = 4 * PP;                     // all-batch plane elems

    if (ws_size >= FULL * 2 * 5) {
        // full-batch path: 5 fp16 planes of 8.4MB
        f16* qh = (f16*)d_ws;
        f16* ql = qh + FULL;
        f16* kh = ql + FULL;
        f16* vv = kh + FULL;
        f16* vT = vv + FULL;
        proj_mfma<<<dim3(256), 256, 0, stream>>>(x, Wq, bq, qh, ql, LOG2E);
        proj_mfma<<<dim3(256), 256, 0, stream>>>(x, Wk, bk, kh, nullptr, 1.f);
        proj_mfma<<<dim3(256), 256, 0, stream>>>(x, Wv, bv, vv, nullptr, 1.f);
        transpose_v<<<dim3(128, 8, 4), dim3(32, 8), 0, stream>>>(vv, vT);
        attn_flash<<<dim3(512), 256, 0, stream>>>(qh, ql, kh, vT, out, 4);
    } else {
        // per-batch fallback (10.5 MB of ws)
        f16* qh = (f16*)d_ws;
        f16* ql = qh + PP;
        f16* kh = ql + PP;
        f16* vv = kh + PP;
        f16* vT = vv + PP;
        for (int b = 0; b < 4; ++b) {
            const float* xb = x + b * PP;
            proj_mfma<<<dim3(64), 256, 0, stream>>>(xb, Wq, bq, qh, ql, LOG2E);
            proj_mfma<<<dim3(64), 256, 0, stream>>>(xb, Wk, bk, kh, nullptr, 1.f);
            proj_mfma<<<dim3(64), 256, 0, stream>>>(xb, Wv, bv, vv, nullptr, 1.f);
            transpose_v<<<dim3(128, 8, 1), dim3(32, 8), 0, stream>>>(vv, vT);
            attn_flash<<<dim3(128), 256, 0, stream>>>(qh, ql, kh, vT, out + b * PP, 1);
        }
    }
}